// Round 1
// baseline (254.939 us; speedup 1.0000x reference)
//
#include <hip/hip_runtime.h>

#define B_ 32
#define C_ 64
#define N_ 2048
#define H_ 128

typedef unsigned short u16;
typedef float f32x4 __attribute__((ext_vector_type(4)));
typedef __bf16 bf16x8 __attribute__((ext_vector_type(8)));
typedef unsigned short u16x4 __attribute__((ext_vector_type(4)));

#define MFMA(a, b, c) __builtin_amdgcn_mfma_f32_16x16x32_bf16(a, b, c, 0, 0, 0)

__device__ __forceinline__ u16 bf16b(float f) {
    union { float f; unsigned u; } v; v.f = f;
    return (u16)((v.u + 0x7FFFu + ((v.u >> 16) & 1u)) >> 16);
}
// XOR swizzle for 128-byte-stride LDS rows (bf16 [*][64]); returns BYTE offset.
__device__ __forceinline__ int swz(int row, int cb) { return row * 128 + (cb ^ ((row & 7) << 4)); }
// same for 256-byte-stride rows (bf16 [*][128])
__device__ __forceinline__ int swz256(int row, int cb) { return row * 256 + (cb ^ ((row & 7) << 4)); }

__device__ __forceinline__ bf16x8 cvt8(const float* p, float s) {
    f32x4 a = *(const f32x4*)p, b = *(const f32x4*)(p + 4);
    bf16x8 o;
    o[0] = (__bf16)(a[0] * s); o[1] = (__bf16)(a[1] * s);
    o[2] = (__bf16)(a[2] * s); o[3] = (__bf16)(a[3] * s);
    o[4] = (__bf16)(b[0] * s); o[5] = (__bf16)(b[1] * s);
    o[6] = (__bf16)(b[2] * s); o[7] = (__bf16)(b[3] * s);
    return o;
}

// ---------------------------------------------------------------------------
// Kernel 1: Q = 0.125*wq*x (stored [B,N,C] bf16), K = wk*x ([B,N,C]), V = wv*x
// ([B,C,N]).  Also converts w_ff1/w_ff2 to bf16 once (block 0).
// ---------------------------------------------------------------------------
__global__ __launch_bounds__(256) void qkv_k(
    const float* __restrict__ x,
    const float* __restrict__ wq, const float* __restrict__ wk, const float* __restrict__ wv,
    const float* __restrict__ w1, const float* __restrict__ w2,
    u16* __restrict__ Qg, u16* __restrict__ Kg, u16* __restrict__ Vg,
    u16* __restrict__ w1b, u16* __restrict__ w2b)
{
    const int b = blockIdx.y, nt = blockIdx.x, t = threadIdx.x;
    const int lane = t & 63, wave = t >> 6, g = lane >> 4, r16 = lane & 15;
    __shared__ __align__(16) u16 xT[128 * 64];   // swizzled bf16 [n_local][c]
    const int n0 = nt * 128;

    // weight fragments: pattern W[(r16+16*tile)*64 + 8*g + 32*kc .. +7]
    bf16x8 wqf[4][2], wkf[4][2], wvf[4][2];
#pragma unroll
    for (int jt = 0; jt < 4; ++jt)
#pragma unroll
        for (int kc = 0; kc < 2; ++kc) {
            const int ro = (r16 + 16 * jt) * 64 + 8 * g + 32 * kc;
            wqf[jt][kc] = cvt8(wq + ro, 0.125f);   // fold 1/sqrt(C) into Q
            wkf[jt][kc] = cvt8(wk + ro, 1.0f);
            wvf[jt][kc] = cvt8(wv + ro, 1.0f);
        }

    { // stage x tile transposed (n-major) + swizzled, as bf16
        int c = t >> 5;
        const int nn = (t & 31) * 4;
#pragma unroll
        for (int pass = 0; pass < 8; ++pass, c += 8) {
            f32x4 v = *(const f32x4*)&x[(size_t)(b * 64 + c) * 2048 + n0 + nn];
#pragma unroll
            for (int j = 0; j < 4; ++j)
                xT[swz(nn + j, 2 * c) >> 1] = bf16b(v[j]);
        }
    }
    if (b == 0 && nt == 0) {
        for (int i = t; i < H_ * C_; i += 256) w1b[i] = bf16b(w1[i]);
        for (int i = t; i < C_ * H_; i += 256) w2b[i] = bf16b(w2[i]);
    }
    __syncthreads();

#pragma unroll
    for (int p = 0; p < 2; ++p) {
        const int nt16 = wave * 2 + p;
        bf16x8 xa[2];  // serves as A (i=n) for Q/K and as B (j=n) for V
#pragma unroll
        for (int kc = 0; kc < 2; ++kc)
            xa[kc] = *(const bf16x8*)&xT[swz(nt16 * 16 + r16, 16 * g + 64 * kc) >> 1];
#pragma unroll
        for (int jt = 0; jt < 4; ++jt) {
            f32x4 aq = {0.f, 0.f, 0.f, 0.f}, ak = {0.f, 0.f, 0.f, 0.f};
            aq = MFMA(xa[0], wqf[jt][0], aq); aq = MFMA(xa[1], wqf[jt][1], aq);
            ak = MFMA(xa[0], wkf[jt][0], ak); ak = MFMA(xa[1], wkf[jt][1], ak);
#pragma unroll
            for (int r = 0; r < 4; ++r) {
                const int n = n0 + nt16 * 16 + 4 * g + r, o = jt * 16 + r16;
                Qg[(size_t)(b * 2048 + n) * 64 + o] = bf16b(aq[r]);
                Kg[(size_t)(b * 2048 + n) * 64 + o] = bf16b(ak[r]);
            }
        }
#pragma unroll
        for (int it = 0; it < 4; ++it) {
            f32x4 av = {0.f, 0.f, 0.f, 0.f};
            av = MFMA(wvf[it][0], xa[0], av);
            av = MFMA(wvf[it][1], xa[1], av);
#pragma unroll
            for (int r = 0; r < 4; ++r) {
                const int o = it * 16 + 4 * g + r, n = n0 + nt16 * 16 + r16;
                Vg[(size_t)(b * 64 + o) * 2048 + n] = bf16b(av[r]);
            }
        }
    }
}

// ---------------------------------------------------------------------------
// Kernel 2: flash attention.  Per wave: 16 Q rows; loop 64-col K/V tiles with
// online softmax.  Epilogue: y[B,N,C] = x + x_r.
// ---------------------------------------------------------------------------
__global__ __launch_bounds__(256) void attn_k(
    const u16* __restrict__ Qg, const u16* __restrict__ Kg, const u16* __restrict__ Vg,
    const float* __restrict__ x, float* __restrict__ y)
{
    const int b = blockIdx.y, nb = blockIdx.x, t = threadIdx.x;
    const int lane = t & 63, wave = t >> 6, g = lane >> 4, r16 = lane & 15;
    __shared__ __align__(16) u16 Kt[64 * 64];      // swizzled [m][c]
    __shared__ __align__(16) u16 Vt[64 * 64];      // swizzled [c][m]
    __shared__ __align__(16) u16 Pl[4][16 * 64];   // per-wave swizzled P [n][m]

    const int n0 = nb * 64 + wave * 16;
    bf16x8 qf[2];
#pragma unroll
    for (int kc = 0; kc < 2; ++kc)
        qf[kc] = *(const bf16x8*)&Qg[(size_t)(b * 2048 + n0 + r16) * 64 + 8 * g + 32 * kc];

    f32x4 acc[4];
    float mrun[4], lrun[4];
#pragma unroll
    for (int ct = 0; ct < 4; ++ct) acc[ct] = (f32x4){0.f, 0.f, 0.f, 0.f};
#pragma unroll
    for (int r = 0; r < 4; ++r) { mrun[r] = -1e30f; lrun[r] = 0.f; }

#pragma unroll 1
    for (int kv = 0; kv < N_; kv += 64) {
        __syncthreads();
        { // stage K,V tiles (coalesced global, swizzled LDS)
            const int mr = t >> 2, ch = t & 3;
            const u16* ks = &Kg[(size_t)(b * 2048 + kv + mr) * 64 + ch * 16];
            *(uint4*)&Kt[swz(mr, ch * 32) >> 1]      = *(const uint4*)ks;
            *(uint4*)&Kt[swz(mr, ch * 32 + 16) >> 1] = *(const uint4*)(ks + 8);
            const u16* vs = &Vg[(size_t)(b * 64 + mr) * 2048 + kv + ch * 16];
            *(uint4*)&Vt[swz(mr, ch * 32) >> 1]      = *(const uint4*)vs;
            *(uint4*)&Vt[swz(mr, ch * 32 + 16) >> 1] = *(const uint4*)(vs + 8);
        }
        __syncthreads();

        // S = Q * K^T   (pre-scaled by 1/8 via Q)
        f32x4 s[4];
#pragma unroll
        for (int jt = 0; jt < 4; ++jt) {
            f32x4 a = {0.f, 0.f, 0.f, 0.f};
#pragma unroll
            for (int kc = 0; kc < 2; ++kc) {
                bf16x8 kf = *(const bf16x8*)&Kt[swz(jt * 16 + r16, 16 * g + 64 * kc) >> 1];
                a = MFMA(qf[kc], kf, a);
            }
            s[jt] = a;
        }
        // online softmax: row stats live across lanes 0..15 of each 16-group
        float pm[4];
#pragma unroll
        for (int r = 0; r < 4; ++r)
            pm[r] = fmaxf(fmaxf(s[0][r], s[1][r]), fmaxf(s[2][r], s[3][r]));
#pragma unroll
        for (int d = 1; d <= 8; d <<= 1)
#pragma unroll
            for (int r = 0; r < 4; ++r)
                pm[r] = fmaxf(pm[r], __shfl_xor(pm[r], d, 64));
        float al[4], rs[4];
#pragma unroll
        for (int r = 0; r < 4; ++r) {
            const float mn = fmaxf(mrun[r], pm[r]);
            al[r] = __expf(mrun[r] - mn);
            mrun[r] = mn;
            rs[r] = 0.f;
        }
        u16 pbits[4][4];
#pragma unroll
        for (int jt = 0; jt < 4; ++jt)
#pragma unroll
            for (int r = 0; r < 4; ++r) {
                const float pv = __expf(s[jt][r] - mrun[r]);
                rs[r] += pv;
                pbits[jt][r] = bf16b(pv);
            }
#pragma unroll
        for (int d = 1; d <= 8; d <<= 1)
#pragma unroll
            for (int r = 0; r < 4; ++r)
                rs[r] += __shfl_xor(rs[r], d, 64);
#pragma unroll
        for (int r = 0; r < 4; ++r) lrun[r] = lrun[r] * al[r] + rs[r];
#pragma unroll
        for (int ct = 0; ct < 4; ++ct)
#pragma unroll
            for (int r = 0; r < 4; ++r) acc[ct][r] *= al[r];

        // P -> LDS (D-layout scatter), read back as A fragments
#pragma unroll
        for (int jt = 0; jt < 4; ++jt)
#pragma unroll
            for (int r = 0; r < 4; ++r) {
                const int row = 4 * g + r;
                Pl[wave][swz(row, 2 * (jt * 16 + r16)) >> 1] = pbits[jt][r];
            }
        bf16x8 pf[2];
#pragma unroll
        for (int kc = 0; kc < 2; ++kc)
            pf[kc] = *(const bf16x8*)&Pl[wave][swz(r16, 16 * g + 64 * kc) >> 1];
#pragma unroll
        for (int ct = 0; ct < 4; ++ct)
#pragma unroll
            for (int kc = 0; kc < 2; ++kc) {
                bf16x8 vf = *(const bf16x8*)&Vt[swz(ct * 16 + r16, 16 * g + 64 * kc) >> 1];
                acc[ct] = MFMA(pf[kc], vf, acc[ct]);
            }
    }

    // epilogue: y = x + O/l
    float inv[4];
#pragma unroll
    for (int r = 0; r < 4; ++r) inv[r] = 1.0f / lrun[r];
#pragma unroll
    for (int ct = 0; ct < 4; ++ct)
#pragma unroll
        for (int r = 0; r < 4; ++r) {
            const int c = ct * 16 + r16, n = n0 + 4 * g + r;
            const float o = acc[ct][r] * inv[r] + x[(size_t)(b * 64 + c) * 2048 + n];
            y[(size_t)(b * 2048 + n) * 64 + c] = o;
        }
}

// ---------------------------------------------------------------------------
// Reduction: per-channel sum/sumsq over [65536][64] -> per-block partials.
// ---------------------------------------------------------------------------
__global__ __launch_bounds__(256) void reduce_k(
    const float* __restrict__ v, float* __restrict__ psum, float* __restrict__ psq)
{
    const int blk = blockIdx.x, t = threadIdx.x, c = t & 63, rg = t >> 6;
    float s = 0.f, q = 0.f;
    const int row0 = blk * 256;
    for (int i = rg; i < 256; i += 4) {
        const float val = v[(size_t)(row0 + i) * 64 + c];
        s += val; q += val * val;
    }
    __shared__ float ls[4][64], lq[4][64];
    ls[rg][c] = s; lq[rg][c] = q;
    __syncthreads();
    if (t < 64) {
        psum[blk * 64 + t] = ls[0][t] + ls[1][t] + ls[2][t] + ls[3][t];
        psq[blk * 64 + t]  = lq[0][t] + lq[1][t] + lq[2][t] + lq[3][t];
    }
}

__global__ __launch_bounds__(256) void finalize_k(
    const float* __restrict__ psum, const float* __restrict__ psq,
    const float* __restrict__ gamma, const float* __restrict__ beta,
    float* __restrict__ ss) // ss[0..63]=scale, ss[64..127]=shift
{
    const int t = threadIdx.x, c = t & 63, g = t >> 6;
    float s = 0.f, q = 0.f;
    for (int bl = g; bl < 256; bl += 4) { s += psum[bl * 64 + c]; q += psq[bl * 64 + c]; }
    __shared__ float ls[4][64], lq[4][64];
    ls[g][c] = s; lq[g][c] = q;
    __syncthreads();
    if (t < 64) {
        s = ls[0][t] + ls[1][t] + ls[2][t] + ls[3][t];
        q = lq[0][t] + lq[1][t] + lq[2][t] + lq[3][t];
        const float mean = s * (1.0f / 65536.0f);
        const float var  = q * (1.0f / 65536.0f) - mean * mean;
        const float sc   = rsqrtf(var + 1e-5f) * gamma[t];
        ss[t] = sc;
        ss[64 + t] = beta[t] - mean * sc;
    }
}

// ---------------------------------------------------------------------------
// Kernel: h = BN1(y); ff = W2 * lrelu(W1 * h); z = h + ff   ([B,N,C] f32)
// ---------------------------------------------------------------------------
__global__ __launch_bounds__(256) void ff_k(
    const float* __restrict__ y, const float* __restrict__ ss1,
    const u16* __restrict__ w1b, const u16* __restrict__ w2b,
    float* __restrict__ z)
{
    const int b = blockIdx.y, nt = blockIdx.x, t = threadIdx.x;
    const int lane = t & 63, wave = t >> 6, g = lane >> 4, r16 = lane & 15;
    __shared__ __align__(16) u16 hT[64 * 64];       // swizzled bf16 [n][c]
    __shared__ __align__(16) float hf[64 * 68];     // f32 [n][c], pad 68
    __shared__ __align__(16) u16 pb[4][16 * 128];   // per-wave swizzled [n][h]
    __shared__ float sc1[64], sh1[64];
    if (t < 64) { sc1[t] = ss1[t]; sh1[t] = ss1[64 + t]; }
    __syncthreads();
    const int n0 = nt * 64;
    {
        const int i = t >> 2, c0 = (t & 3) * 16;
        u16 hb[16] __attribute__((aligned(16)));
#pragma unroll
        for (int q4 = 0; q4 < 4; ++q4) {
            const int c = c0 + 4 * q4;
            f32x4 v = *(const f32x4*)&y[(size_t)(b * 2048 + n0 + i) * 64 + c];
            f32x4 hv;
#pragma unroll
            for (int j = 0; j < 4; ++j) hv[j] = v[j] * sc1[c + j] + sh1[c + j];
            *(f32x4*)&hf[i * 68 + c] = hv;
#pragma unroll
            for (int j = 0; j < 4; ++j) hb[4 * q4 + j] = bf16b(hv[j]);
        }
        *(uint4*)&hT[swz(i, 2 * c0) >> 1]      = *(const uint4*)&hb[0];
        *(uint4*)&hT[swz(i, 2 * c0 + 16) >> 1] = *(const uint4*)&hb[8];
    }
    __syncthreads();

    bf16x8 ha[2];
#pragma unroll
    for (int kc = 0; kc < 2; ++kc)
        ha[kc] = *(const bf16x8*)&hT[swz(wave * 16 + r16, 16 * g + 64 * kc) >> 1];
    // ff1 = lrelu(W1 * h), written transposed to pb
#pragma unroll
    for (int it = 0; it < 8; ++it) {
        f32x4 a = {0.f, 0.f, 0.f, 0.f};
#pragma unroll
        for (int kc = 0; kc < 2; ++kc) {
            bf16x8 w1f = *(const bf16x8*)&w1b[(r16 + 16 * it) * 64 + 8 * g + 32 * kc];
            a = MFMA(w1f, ha[kc], a);
        }
        u16x4 pk;
#pragma unroll
        for (int r = 0; r < 4; ++r) {
            const float rv = a[r] >= 0.f ? a[r] : 0.2f * a[r];
            pk[r] = bf16b(rv);
        }
        *(u16x4*)&pb[wave][swz256(r16, 2 * (16 * it + 4 * g)) >> 1] = pk;
    }
    // ff2 = W2 * ff1 ; z = h + ff2
    bf16x8 pa[4];
#pragma unroll
    for (int kc = 0; kc < 4; ++kc)
        pa[kc] = *(const bf16x8*)&pb[wave][swz256(r16, 16 * g + 64 * kc) >> 1];
#pragma unroll
    for (int jt = 0; jt < 4; ++jt) {
        f32x4 a = {0.f, 0.f, 0.f, 0.f};
#pragma unroll
        for (int kc = 0; kc < 4; ++kc) {
            bf16x8 w2f = *(const bf16x8*)&w2b[(r16 + 16 * jt) * 128 + 8 * g + 32 * kc];
            a = MFMA(pa[kc], w2f, a);
        }
#pragma unroll
        for (int r = 0; r < 4; ++r) {
            const int nl = wave * 16 + 4 * g + r, c = jt * 16 + r16;
            z[(size_t)(b * 2048 + n0 + nl) * 64 + c] = hf[nl * 68 + c] + a[r];
        }
    }
}

// ---------------------------------------------------------------------------
// Kernel: out[B,C,N] = BN2(z[B,N,C])  (LDS transpose)
// ---------------------------------------------------------------------------
__global__ __launch_bounds__(256) void bnout_k(
    const float* __restrict__ z, const float* __restrict__ ss2, float* __restrict__ out)
{
    const int b = blockIdx.y, nt = blockIdx.x, t = threadIdx.x;
    __shared__ float tile[64 * 65];
    __shared__ float sc2[64], sh2[64];
    if (t < 64) { sc2[t] = ss2[t]; sh2[t] = ss2[64 + t]; }
    __syncthreads();
    const int n0 = nt * 64;
    {
        const int i = t >> 2, c0 = (t & 3) * 16;
#pragma unroll
        for (int q4 = 0; q4 < 4; ++q4) {
            const int c = c0 + 4 * q4;
            f32x4 v = *(const f32x4*)&z[(size_t)(b * 2048 + n0 + i) * 64 + c];
#pragma unroll
            for (int j = 0; j < 4; ++j)
                tile[(i)*65 + c + j] = v[j] * sc2[c + j] + sh2[c + j];
        }
    }
    __syncthreads();
    {
        const int c = t >> 2, j0 = (t & 3) * 16;
#pragma unroll
        for (int q4 = 0; q4 < 4; ++q4) {
            f32x4 ov;
#pragma unroll
            for (int j = 0; j < 4; ++j)
                ov[j] = tile[(j0 + 4 * q4 + j) * 65 + c];
            *(f32x4*)&out[(size_t)(b * 64 + c) * 2048 + n0 + j0 + 4 * q4] = ov;
        }
    }
}

extern "C" void kernel_launch(void* const* d_in, const int* in_sizes, int n_in,
                              void* d_out, int out_size, void* d_ws, size_t ws_size,
                              hipStream_t stream)
{
    const float* x   = (const float*)d_in[0];
    const float* wq  = (const float*)d_in[1];
    const float* wk  = (const float*)d_in[2];
    const float* wv  = (const float*)d_in[3];
    const float* w1  = (const float*)d_in[4];
    const float* w2  = (const float*)d_in[5];
    const float* g1  = (const float*)d_in[6];
    const float* be1 = (const float*)d_in[7];
    const float* g2  = (const float*)d_in[8];
    const float* be2 = (const float*)d_in[9];
    float* out = (float*)d_out;

    char* w = (char*)d_ws;
    u16* Qg = (u16*)w;   w += (size_t)B_ * N_ * C_ * 2;
    u16* Kg = (u16*)w;   w += (size_t)B_ * N_ * C_ * 2;
    u16* Vg = (u16*)w;   w += (size_t)B_ * N_ * C_ * 2;
    float* y = (float*)w; w += (size_t)B_ * N_ * C_ * 4;
    float* z = (float*)w; w += (size_t)B_ * N_ * C_ * 4;
    u16* w1b = (u16*)w;  w += (size_t)H_ * C_ * 2;
    u16* w2b = (u16*)w;  w += (size_t)C_ * H_ * 2;
    float* ps1 = (float*)w; w += 256 * 64 * 4;
    float* pq1 = (float*)w; w += 256 * 64 * 4;
    float* ps2 = (float*)w; w += 256 * 64 * 4;
    float* pq2 = (float*)w; w += 256 * 64 * 4;
    float* ss1 = (float*)w; w += 128 * 4;
    float* ss2 = (float*)w; w += 128 * 4;

    const dim3 blk(256);
    hipLaunchKernelGGL(qkv_k,   dim3(16, 32), blk, 0, stream, x, wq, wk, wv, w1, w2, Qg, Kg, Vg, w1b, w2b);
    hipLaunchKernelGGL(attn_k,  dim3(32, 32), blk, 0, stream, Qg, Kg, Vg, x, y);
    hipLaunchKernelGGL(reduce_k, dim3(256),   blk, 0, stream, y, ps1, pq1);
    hipLaunchKernelGGL(finalize_k, dim3(1),   blk, 0, stream, ps1, pq1, g1, be1, ss1);
    hipLaunchKernelGGL(ff_k,    dim3(32, 32), blk, 0, stream, y, ss1, w1b, w2b, z);
    hipLaunchKernelGGL(reduce_k, dim3(256),   blk, 0, stream, z, ps2, pq2);
    hipLaunchKernelGGL(finalize_k, dim3(1),   blk, 0, stream, ps2, pq2, g2, be2, ss2);
    hipLaunchKernelGGL(bnout_k, dim3(32, 32), blk, 0, stream, z, ss2, out);
}